// Round 8
// baseline (293.491 us; speedup 1.0000x reference)
//
#include <hip/hip_runtime.h>
#include <hip/hip_fp16.h>
#include <hip/hip_bf16.h>
#include <stdint.h>

#define TILE 128
#define BK 32
#define LDST 40   // 32 + 8 pad: 80B row stride keeps 16B alignment, <=2-way bank alias

typedef __attribute__((ext_vector_type(8))) short short8;
typedef __attribute__((ext_vector_type(8))) unsigned short ushort8;
typedef __attribute__((ext_vector_type(4))) float f32x4;

static __device__ __forceinline__ unsigned short f2bf(float f) {
    union { float f; uint32_t u; } v; v.f = f;
    uint32_t u = v.u;
    u += 0x7fffu + ((u >> 16) & 1u);   // RNE
    return (unsigned short)(u >> 16);
}

static __device__ __forceinline__ unsigned int pk_bf16(float a, float b) {
    __hip_bfloat162 h = __float22bfloat162_rn(float2{a, b});   // v_cvt_pk_bf16_f32 (RNE)
    union { __hip_bfloat162 h; unsigned int u; } c; c.h = h;
    return c.u;
}

// ---------------- W transpose+convert: Wt[n][k] bf16 from W[k][n] fp32 ----------------
__global__ __launch_bounds__(256)
void wt_kernel(const float* __restrict__ W, unsigned short* __restrict__ Wt)
{
    __shared__ float s[32][33];
    const int tx = threadIdx.x;          // 0..31
    const int ty = threadIdx.y;          // 0..7
    const int kBase = blockIdx.x * 32;
    const int nBase = blockIdx.y * 32;
    #pragma unroll
    for (int j = 0; j < 4; ++j)
        s[ty + 8 * j][tx] = W[(size_t)(kBase + ty + 8 * j) * 512 + nBase + tx];
    __syncthreads();
    #pragma unroll
    for (int j = 0; j < 4; ++j)
        Wt[(size_t)(nBase + ty + 8 * j) * 512 + kBase + tx] = f2bf(s[tx][ty + 8 * j]);
}

// ---------------- xp = x @ W + b  (M=65536, K=512, N=512) ----------------
// R2/R7 structure + register prefetch (T14-lite): tile kt held in regs, written
// to LDS, then kt+BK's global loads ISSUE before the MFMA phase -> the vmcnt(0)
// drain before next iter's ds_write waits on loads aged by a full MFMA phase.
template <bool F16OUT>
__global__ __launch_bounds__(256, 4)
void gemm_bias_kernel(const float* __restrict__ X, const unsigned short* __restrict__ Wt,
                      const float* __restrict__ bias,
                      float* __restrict__ out32, __half* __restrict__ xpT)
{
    __shared__ unsigned short As[TILE * LDST];
    __shared__ unsigned short Bs[TILE * LDST];

    const int tid = threadIdx.x;

    // XCD-chunked tile remap: lin%8 -> XCD; each XCD gets 64 consecutive m-tiles
    // x 4 n-tiles so blocks sharing an X stripe share an L2.
    const int lin = blockIdx.x;          // 0..2047
    const int xcd = lin & 7;
    const int idx = lin >> 3;            // 0..255
    const int rowBase = (xcd * 64 + (idx >> 2)) * TILE;
    const int colBase = (idx & 3) * TILE;

    const int wave  = tid >> 6;
    const int lane  = tid & 63;
    const int m16   = lane & 15;
    const int quad  = lane >> 4;
    const int waveM = wave & 1;
    const int waveN = wave >> 1;

    f32x4 acc[4][4] = {};

    const int srow = tid >> 2;   // 0..63
    const int sc4  = tid & 3;    // 0..3 (k-chunk of 8)

    const float* aSrc0 = X + (size_t)(rowBase + srow) * 512 + sc4 * 8;        // p=0 row
    const float* aSrc1 = X + (size_t)(rowBase + 64 + srow) * 512 + sc4 * 8;   // p=1 row
    const unsigned short* bSrc0 = Wt + (size_t)(colBase + srow) * 512 + sc4 * 8;
    const unsigned short* bSrc1 = Wt + (size_t)(colBase + 64 + srow) * 512 + sc4 * 8;

    // register staging buffers (in flight across the MFMA phase)
    float4 ra[2][2];
    ushort8 rb[2];

    // prologue: load kt=0
    ra[0][0] = *(const float4*)(aSrc0);     ra[0][1] = *(const float4*)(aSrc0 + 4);
    ra[1][0] = *(const float4*)(aSrc1);     ra[1][1] = *(const float4*)(aSrc1 + 4);
    rb[0] = *(const ushort8*)(bSrc0);
    rb[1] = *(const ushort8*)(bSrc1);

    for (int kt = 0; kt < 512; kt += BK) {
        // ---- write staged regs -> LDS (cvt fp32->bf16 for A) ----
        #pragma unroll
        for (int p = 0; p < 2; ++p) {
            union { ushort8 s8; unsigned int u[4]; } us;
            us.u[0] = pk_bf16(ra[p][0].x, ra[p][0].y); us.u[1] = pk_bf16(ra[p][0].z, ra[p][0].w);
            us.u[2] = pk_bf16(ra[p][1].x, ra[p][1].y); us.u[3] = pk_bf16(ra[p][1].z, ra[p][1].w);
            *(ushort8*)(&As[(p * 64 + srow) * LDST + sc4 * 8]) = us.s8;
            *(ushort8*)(&Bs[(p * 64 + srow) * LDST + sc4 * 8]) = rb[p];
        }
        __syncthreads();

        // ---- issue next K-step's global loads (overlap with MFMA below) ----
        if (kt + BK < 512) {
            const int ko = kt + BK;
            ra[0][0] = *(const float4*)(aSrc0 + ko);     ra[0][1] = *(const float4*)(aSrc0 + ko + 4);
            ra[1][0] = *(const float4*)(aSrc1 + ko);     ra[1][1] = *(const float4*)(aSrc1 + ko + 4);
            rb[0] = *(const ushort8*)(bSrc0 + ko);
            rb[1] = *(const ushort8*)(bSrc1 + ko);
        }

        short8 a_frag[4], b_frag[4];
        #pragma unroll
        for (int mi = 0; mi < 4; ++mi)
            a_frag[mi] = *(const short8*)&As[(waveM * 64 + mi * 16 + m16) * LDST + quad * 8];
        #pragma unroll
        for (int ni = 0; ni < 4; ++ni)
            b_frag[ni] = *(const short8*)&Bs[(waveN * 64 + ni * 16 + m16) * LDST + quad * 8];

        #pragma unroll
        for (int mi = 0; mi < 4; ++mi)
            #pragma unroll
            for (int ni = 0; ni < 4; ++ni) {
                if (F16OUT)   // swapped -> acc holds C^T fragment (lane axis = t)
                    acc[mi][ni] = __builtin_amdgcn_mfma_f32_16x16x32_bf16(
                        b_frag[ni], a_frag[mi], acc[mi][ni], 0, 0, 0);
                else
                    acc[mi][ni] = __builtin_amdgcn_mfma_f32_16x16x32_bf16(
                        a_frag[mi], b_frag[ni], acc[mi][ni], 0, 0, 0);
            }
        __syncthreads();
    }

    if (F16OUT) {
        // transposed frag: col(lane&15)=t, row(quad*4+reg)=r
        const int bb = rowBase >> 10;          // whole 128-row tile sits in one b
        #pragma unroll
        for (int ni = 0; ni < 4; ++ni) {
            int r0 = colBase + waveN * 64 + ni * 16 + quad * 4;
            float4 b4 = *(const float4*)&bias[r0];
            #pragma unroll
            for (int mi = 0; mi < 4; ++mi) {
                int tt = (rowBase + waveM * 64 + mi * 16 + m16) & 1023;
                #pragma unroll
                for (int r = 0; r < 4; ++r) {
                    float v = acc[mi][ni][r] + ((const float*)&b4)[r];
                    xpT[((size_t)bb * 512 + r0 + r) * 1024 + tt] = __float2half_rn(v);
                }
            }
        }
    } else {
        // standard layout: col=lane&15, row=quad*4+reg
        #pragma unroll
        for (int ni = 0; ni < 4; ++ni) {
            int col = colBase + waveN * 64 + ni * 16 + m16;
            float bv = bias[col];
            #pragma unroll
            for (int mi = 0; mi < 4; ++mi) {
                int row0 = rowBase + waveM * 64 + mi * 16 + quad * 4;
                #pragma unroll
                for (int r = 0; r < 4; ++r) {
                    float v = acc[mi][ni][r] + bv;
                    out32[(size_t)(row0 + r) * 512 + col] = v;
                }
            }
        }
    }
}

// ---------------- scan: h_t = relu(xp_t + u*h_{t-1}), h_0 = 1 ----------------
// xpT layout [B][R][T]: each lane streams a contiguous 2KB row via ushort8 (16B/lane),
// 128-deep double-buffered prefetch. ~30us: at the 192MB/6.3TB/s roofline.
#define SUNR 128

__global__ __launch_bounds__(64)
void scan_t_kernel(const __half* __restrict__ xpT, float* __restrict__ out,
                   const float* __restrict__ u)
{
    const int gid = blockIdx.x * 64 + threadIdx.x;  // 0..32767
    const int b = gid >> 9;
    const int r = gid & 511;
    const float ur = u[r];
    const unsigned short* p = (const unsigned short*)xpT + ((size_t)b * 512 + r) * 1024;
    float* po = out + (size_t)b * 1024 * 512 + r;

    float h = 1.0f;
    ushort8 cur[SUNR / 8], nxt[SUNR / 8];
    #pragma unroll
    for (int j = 0; j < SUNR / 8; ++j) cur[j] = *(const ushort8*)(p + j * 8);

    for (int t0 = 0; t0 < 1024; t0 += SUNR) {
        const bool more = (t0 + SUNR) < 1024;
        if (more) {
            #pragma unroll
            for (int j = 0; j < SUNR / 8; ++j)
                nxt[j] = *(const ushort8*)(p + t0 + SUNR + j * 8);
        }
        #pragma unroll
        for (int j = 0; j < SUNR / 8; ++j) {
            #pragma unroll
            for (int e = 0; e < 8; ++e) {
                float xv = __half2float(__ushort_as_half(cur[j][e]));
                h = fmaxf(fmaf(ur, h, xv), 0.0f);
                __builtin_nontemporal_store(h, po + (size_t)(t0 + j * 8 + e) * 512);
            }
        }
        #pragma unroll
        for (int j = 0; j < SUNR / 8; ++j) cur[j] = nxt[j];
    }
}

// fp32 in-place fallback (xp in out, [B,T,R] layout)
#define UNR 32
__global__ __launch_bounds__(64)
void scan_f32_kernel(float* __restrict__ out, const float* __restrict__ u)
{
    const int gid = blockIdx.x * 64 + threadIdx.x;
    const int b = gid >> 9;
    const int r = gid & 511;
    const float ur = u[r];
    float* p = out + (size_t)b * 1024 * 512 + r;

    float h = 1.0f;
    float cur[UNR], nxt[UNR];
    #pragma unroll
    for (int j = 0; j < UNR; ++j) cur[j] = p[(size_t)j * 512];

    for (int t0 = 0; t0 < 1024; t0 += UNR) {
        const bool more = (t0 + UNR) < 1024;
        const float* pn = p + (size_t)(t0 + UNR) * 512;
        if (more) {
            #pragma unroll
            for (int j = 0; j < UNR; ++j) nxt[j] = pn[(size_t)j * 512];
        }
        #pragma unroll
        for (int j = 0; j < UNR; ++j) {
            h = fmaxf(fmaf(ur, h, cur[j]), 0.0f);
            p[(size_t)(t0 + j) * 512] = h;
        }
        #pragma unroll
        for (int j = 0; j < UNR; ++j) cur[j] = nxt[j];
    }
}

extern "C" void kernel_launch(void* const* d_in, const int* in_sizes, int n_in,
                              void* d_out, int out_size, void* d_ws, size_t ws_size,
                              hipStream_t stream) {
    const float* x = (const float*)d_in[0];   // [64,1024,512]
    const float* W = (const float*)d_in[1];   // [512,512]
    const float* u = (const float*)d_in[2];   // [512]
    const float* b = (const float*)d_in[3];   // [512]
    float* out = (float*)d_out;               // [64,1024,512] fp32

    const size_t WT_BYTES = (size_t)512 * 512 * 2;              // 512 KB bf16 Wt
    const size_t XP_BYTES = (size_t)64 * 1024 * 512 * 2;        // 64 MB fp16 xpT
    unsigned short* Wt = (unsigned short*)d_ws;
    __half* xp16 = (__half*)((char*)d_ws + WT_BYTES);
    const bool f16path = ws_size >= WT_BYTES + XP_BYTES;        // deterministic -> graph-safe

    dim3 tgrid(16, 16), tblk(32, 8);
    wt_kernel<<<tgrid, tblk, 0, stream>>>(W, Wt);

    dim3 grid(2048);                          // 1D; XCD-chunked remap inside kernel
    if (f16path) {
        gemm_bias_kernel<true><<<grid, 256, 0, stream>>>(x, Wt, b, nullptr, xp16);
        scan_t_kernel<<<512, 64, 0, stream>>>(xp16, out, u);
    } else {
        gemm_bias_kernel<false><<<grid, 256, 0, stream>>>(x, Wt, b, out, nullptr);
        scan_f32_kernel<<<512, 64, 0, stream>>>(out, u);
    }
}

// Round 9
// 291.728 us; speedup vs baseline: 1.0060x; 1.0060x over previous
//
#include <hip/hip_runtime.h>
#include <hip/hip_fp16.h>
#include <hip/hip_bf16.h>
#include <stdint.h>

#define TILE 128
#define BK 32
#define LDST 40   // fallback-path pad only

typedef __attribute__((ext_vector_type(8))) short short8;
typedef __attribute__((ext_vector_type(8))) unsigned short ushort8;
typedef __attribute__((ext_vector_type(4))) float f32x4;

typedef const __attribute__((address_space(1))) void* gptr_t;
typedef __attribute__((address_space(3))) void* lptr_t;

static __device__ __forceinline__ unsigned short f2bf(float f) {
    union { float f; uint32_t u; } v; v.f = f;
    uint32_t u = v.u;
    u += 0x7fffu + ((u >> 16) & 1u);   // RNE
    return (unsigned short)(u >> 16);
}

static __device__ __forceinline__ unsigned int pk_bf16(float a, float b) {
    __hip_bfloat162 h = __float22bfloat162_rn(float2{a, b});   // v_cvt_pk_bf16_f32 (RNE)
    union { __hip_bfloat162 h; unsigned int u; } c; c.h = h;
    return c.u;
}

// ---------------- W transpose+convert: Wt[n][k] bf16 from W[k][n] fp32 ----------------
__global__ __launch_bounds__(256)
void wt_kernel(const float* __restrict__ W, unsigned short* __restrict__ Wt)
{
    __shared__ float s[32][33];
    const int tx = threadIdx.x;          // 0..31
    const int ty = threadIdx.y;          // 0..7
    const int kBase = blockIdx.x * 32;
    const int nBase = blockIdx.y * 32;
    #pragma unroll
    for (int j = 0; j < 4; ++j)
        s[ty + 8 * j][tx] = W[(size_t)(kBase + ty + 8 * j) * 512 + nBase + tx];
    __syncthreads();
    #pragma unroll
    for (int j = 0; j < 4; ++j)
        Wt[(size_t)(nBase + ty + 8 * j) * 512 + kBase + tx] = f2bf(s[tx][ty + 8 * j]);
}

// ---------------- X fp32 -> bf16 pre-pass (Xb in the out buffer as scratch) ----------
// 33.55M elements, 16/thread/iter, 4 iters at 2048x256. Coalesced 64B read, 32B write.
__global__ __launch_bounds__(256)
void xb_kernel(const float* __restrict__ X, unsigned short* __restrict__ Xb)
{
    size_t i = ((size_t)blockIdx.x * 256 + threadIdx.x) * 16;
    const size_t stride = (size_t)2048 * 256 * 16;
    #pragma unroll
    for (int it = 0; it < 4; ++it, i += stride) {
        float4 v0 = *(const float4*)(X + i);
        float4 v1 = *(const float4*)(X + i + 4);
        float4 v2 = *(const float4*)(X + i + 8);
        float4 v3 = *(const float4*)(X + i + 12);
        union { ushort8 s8; unsigned int u[4]; } a, b;
        a.u[0] = pk_bf16(v0.x, v0.y); a.u[1] = pk_bf16(v0.z, v0.w);
        a.u[2] = pk_bf16(v1.x, v1.y); a.u[3] = pk_bf16(v1.z, v1.w);
        b.u[0] = pk_bf16(v2.x, v2.y); b.u[1] = pk_bf16(v2.z, v2.w);
        b.u[2] = pk_bf16(v3.x, v3.y); b.u[3] = pk_bf16(v3.z, v3.w);
        *(ushort8*)(Xb + i)     = a.s8;
        *(ushort8*)(Xb + i + 8) = b.s8;
    }
}

// ---------------- xp = Xb @ Wt^T + b, bf16 in, fp16 out (m97 structure) ----------------
// Both operands staged via global_load_lds dwordx4 into LINEAR LDS (no reg round-trip,
// no pad -- m173). Stage phase = 4 DMA issues/thread. Swapped MFMA -> C^T (lane axis = t)
// -> coalesced 2B stores into xpT[b][r][t].
__global__ __launch_bounds__(256, 2)
void gemm_xb_kernel(const unsigned short* __restrict__ Xb, const unsigned short* __restrict__ Wt,
                    const float* __restrict__ bias, __half* __restrict__ xpT)
{
    __shared__ unsigned short As[TILE * BK];   // 8 KB linear
    __shared__ unsigned short Bs[TILE * BK];   // 8 KB linear

    const int tid = threadIdx.x;

    // XCD-chunked tile remap: lin%8 -> XCD; 64 consecutive m-tiles x 4 n-tiles per XCD.
    const int lin = blockIdx.x;          // 0..2047
    const int xcd = lin & 7;
    const int idx = lin >> 3;            // 0..255
    const int rowBase = (xcd * 64 + (idx >> 2)) * TILE;
    const int colBase = (idx & 3) * TILE;

    const int wave  = tid >> 6;
    const int lane  = tid & 63;
    const int m16   = lane & 15;
    const int quad  = lane >> 4;
    const int waveM = wave & 1;
    const int waveN = wave >> 1;

    f32x4 acc[4][4] = {};

    // staging map: tile = 512 chunks of 16B; chunk c: m = c>>2, j = c&3 (16B within row)
    // thread covers c = (wave*2+p)*64 + lane; LDS dest = wave-uniform cbase*16 + lane*16.
    const int c0 = wave * 2 * 64 + lane;
    const int m0 = c0 >> 2, j0 = c0 & 3;
    const int c1 = (wave * 2 + 1) * 64 + lane;
    const int m1 = c1 >> 2, j1 = c1 & 3;

    const unsigned short* aS0 = Xb + (size_t)(rowBase + m0) * 512 + j0 * 8;
    const unsigned short* aS1 = Xb + (size_t)(rowBase + m1) * 512 + j1 * 8;
    const unsigned short* bS0 = Wt + (size_t)(colBase + m0) * 512 + j0 * 8;
    const unsigned short* bS1 = Wt + (size_t)(colBase + m1) * 512 + j1 * 8;

    for (int kt = 0; kt < 512; kt += BK) {
        __builtin_amdgcn_global_load_lds((gptr_t)(aS0 + kt),
            (lptr_t)((char*)As + (wave * 2) * 64 * 16), 16, 0, 0);
        __builtin_amdgcn_global_load_lds((gptr_t)(aS1 + kt),
            (lptr_t)((char*)As + (wave * 2 + 1) * 64 * 16), 16, 0, 0);
        __builtin_amdgcn_global_load_lds((gptr_t)(bS0 + kt),
            (lptr_t)((char*)Bs + (wave * 2) * 64 * 16), 16, 0, 0);
        __builtin_amdgcn_global_load_lds((gptr_t)(bS1 + kt),
            (lptr_t)((char*)Bs + (wave * 2 + 1) * 64 * 16), 16, 0, 0);
        __syncthreads();

        short8 a_frag[4], b_frag[4];
        #pragma unroll
        for (int mi = 0; mi < 4; ++mi)
            a_frag[mi] = *(const short8*)&As[(waveM * 64 + mi * 16 + m16) * BK + quad * 8];
        #pragma unroll
        for (int ni = 0; ni < 4; ++ni)
            b_frag[ni] = *(const short8*)&Bs[(waveN * 64 + ni * 16 + m16) * BK + quad * 8];

        #pragma unroll
        for (int mi = 0; mi < 4; ++mi)
            #pragma unroll
            for (int ni = 0; ni < 4; ++ni)   // swapped -> acc holds C^T fragment
                acc[mi][ni] = __builtin_amdgcn_mfma_f32_16x16x32_bf16(
                    b_frag[ni], a_frag[mi], acc[mi][ni], 0, 0, 0);
        __syncthreads();
    }

    // transposed frag: col(lane&15)=t, row(quad*4+reg)=r
    const int bb = rowBase >> 10;          // whole 128-row tile sits in one b
    #pragma unroll
    for (int ni = 0; ni < 4; ++ni) {
        int r0 = colBase + waveN * 64 + ni * 16 + quad * 4;
        float4 b4 = *(const float4*)&bias[r0];
        #pragma unroll
        for (int mi = 0; mi < 4; ++mi) {
            int tt = (rowBase + waveM * 64 + mi * 16 + m16) & 1023;
            #pragma unroll
            for (int r = 0; r < 4; ++r) {
                float v = acc[mi][ni][r] + ((const float*)&b4)[r];
                xpT[((size_t)bb * 512 + r0 + r) * 1024 + tt] = __float2half_rn(v);
            }
        }
    }
}

// ---------------- fallback GEMM (fp32 out, reg-staged from fp32 X; R2-verbatim) --------
__global__ __launch_bounds__(256, 2)
void gemm_f32_kernel(const float* __restrict__ X, const unsigned short* __restrict__ Wt,
                     const float* __restrict__ bias, float* __restrict__ out32)
{
    __shared__ unsigned short As[TILE * LDST];
    __shared__ unsigned short Bs[TILE * LDST];

    const int tid = threadIdx.x;
    const int lin = blockIdx.x;
    const int xcd = lin & 7;
    const int idx = lin >> 3;
    const int rowBase = (xcd * 64 + (idx >> 2)) * TILE;
    const int colBase = (idx & 3) * TILE;

    const int wave  = tid >> 6;
    const int lane  = tid & 63;
    const int m16   = lane & 15;
    const int quad  = lane >> 4;
    const int waveM = wave & 1;
    const int waveN = wave >> 1;

    f32x4 acc[4][4] = {};

    const int srow = tid >> 2;
    const int sc4  = tid & 3;

    for (int kt = 0; kt < 512; kt += BK) {
        #pragma unroll
        for (int p = 0; p < 2; ++p) {
            int r = p * 64 + srow;
            const float* src = X + (size_t)(rowBase + r) * 512 + kt + sc4 * 8;
            float4 v0 = *(const float4*)(src);
            float4 v1 = *(const float4*)(src + 4);
            union { ushort8 s8; unsigned int u[4]; } us;
            us.u[0] = pk_bf16(v0.x, v0.y); us.u[1] = pk_bf16(v0.z, v0.w);
            us.u[2] = pk_bf16(v1.x, v1.y); us.u[3] = pk_bf16(v1.z, v1.w);
            *(ushort8*)(&As[r * LDST + sc4 * 8]) = us.s8;
        }
        #pragma unroll
        for (int p = 0; p < 2; ++p) {
            int n = p * 64 + srow;
            ushort8 v = *(const ushort8*)(Wt + (size_t)(colBase + n) * 512 + kt + sc4 * 8);
            *(ushort8*)(&Bs[n * LDST + sc4 * 8]) = v;
        }
        __syncthreads();

        short8 a_frag[4], b_frag[4];
        #pragma unroll
        for (int mi = 0; mi < 4; ++mi)
            a_frag[mi] = *(const short8*)&As[(waveM * 64 + mi * 16 + m16) * LDST + quad * 8];
        #pragma unroll
        for (int ni = 0; ni < 4; ++ni)
            b_frag[ni] = *(const short8*)&Bs[(waveN * 64 + ni * 16 + m16) * LDST + quad * 8];

        #pragma unroll
        for (int mi = 0; mi < 4; ++mi)
            #pragma unroll
            for (int ni = 0; ni < 4; ++ni)
                acc[mi][ni] = __builtin_amdgcn_mfma_f32_16x16x32_bf16(
                    a_frag[mi], b_frag[ni], acc[mi][ni], 0, 0, 0);
        __syncthreads();
    }

    #pragma unroll
    for (int ni = 0; ni < 4; ++ni) {
        int col = colBase + waveN * 64 + ni * 16 + m16;
        float bv = bias[col];
        #pragma unroll
        for (int mi = 0; mi < 4; ++mi) {
            int row0 = rowBase + waveM * 64 + mi * 16 + quad * 4;
            #pragma unroll
            for (int r = 0; r < 4; ++r) {
                float v = acc[mi][ni][r] + bv;
                out32[(size_t)(row0 + r) * 512 + col] = v;
            }
        }
    }
}

// ---------------- scan: h_t = relu(xp_t + u*h_{t-1}), h_0 = 1 ----------------
// xpT layout [B][R][T]: contiguous 2KB row/lane, 128-deep prefetch. ~30us (roofline).
#define SUNR 128

__global__ __launch_bounds__(64)
void scan_t_kernel(const __half* __restrict__ xpT, float* __restrict__ out,
                   const float* __restrict__ u)
{
    const int gid = blockIdx.x * 64 + threadIdx.x;  // 0..32767
    const int b = gid >> 9;
    const int r = gid & 511;
    const float ur = u[r];
    const unsigned short* p = (const unsigned short*)xpT + ((size_t)b * 512 + r) * 1024;
    float* po = out + (size_t)b * 1024 * 512 + r;

    float h = 1.0f;
    ushort8 cur[SUNR / 8], nxt[SUNR / 8];
    #pragma unroll
    for (int j = 0; j < SUNR / 8; ++j) cur[j] = *(const ushort8*)(p + j * 8);

    for (int t0 = 0; t0 < 1024; t0 += SUNR) {
        const bool more = (t0 + SUNR) < 1024;
        if (more) {
            #pragma unroll
            for (int j = 0; j < SUNR / 8; ++j)
                nxt[j] = *(const ushort8*)(p + t0 + SUNR + j * 8);
        }
        #pragma unroll
        for (int j = 0; j < SUNR / 8; ++j) {
            #pragma unroll
            for (int e = 0; e < 8; ++e) {
                float xv = __half2float(__ushort_as_half(cur[j][e]));
                h = fmaxf(fmaf(ur, h, xv), 0.0f);
                __builtin_nontemporal_store(h, po + (size_t)(t0 + j * 8 + e) * 512);
            }
        }
        #pragma unroll
        for (int j = 0; j < SUNR / 8; ++j) cur[j] = nxt[j];
    }
}

// fp32 in-place fallback (xp in out, [B,T,R] layout)
#define UNR 32
__global__ __launch_bounds__(64)
void scan_f32_kernel(float* __restrict__ out, const float* __restrict__ u)
{
    const int gid = blockIdx.x * 64 + threadIdx.x;
    const int b = gid >> 9;
    const int r = gid & 511;
    const float ur = u[r];
    float* p = out + (size_t)b * 1024 * 512 + r;

    float h = 1.0f;
    float cur[UNR], nxt[UNR];
    #pragma unroll
    for (int j = 0; j < UNR; ++j) cur[j] = p[(size_t)j * 512];

    for (int t0 = 0; t0 < 1024; t0 += UNR) {
        const bool more = (t0 + UNR) < 1024;
        const float* pn = p + (size_t)(t0 + UNR) * 512;
        if (more) {
            #pragma unroll
            for (int j = 0; j < UNR; ++j) nxt[j] = pn[(size_t)j * 512];
        }
        #pragma unroll
        for (int j = 0; j < UNR; ++j) {
            h = fmaxf(fmaf(ur, h, cur[j]), 0.0f);
            p[(size_t)(t0 + j) * 512] = h;
        }
        #pragma unroll
        for (int j = 0; j < UNR; ++j) cur[j] = nxt[j];
    }
}

extern "C" void kernel_launch(void* const* d_in, const int* in_sizes, int n_in,
                              void* d_out, int out_size, void* d_ws, size_t ws_size,
                              hipStream_t stream) {
    const float* x = (const float*)d_in[0];   // [64,1024,512]
    const float* W = (const float*)d_in[1];   // [512,512]
    const float* u = (const float*)d_in[2];   // [512]
    const float* b = (const float*)d_in[3];   // [512]
    float* out = (float*)d_out;               // [64,1024,512] fp32 (134 MB)

    const size_t WT_BYTES = (size_t)512 * 512 * 2;              // 512 KB bf16 Wt
    const size_t XP_BYTES = (size_t)64 * 1024 * 512 * 2;        // 64 MB fp16 xpT
    unsigned short* Wt = (unsigned short*)d_ws;
    __half* xp16 = (__half*)((char*)d_ws + WT_BYTES);
    const bool f16path = ws_size >= WT_BYTES + XP_BYTES;        // deterministic -> graph-safe

    dim3 tgrid(16, 16), tblk(32, 8);
    wt_kernel<<<tgrid, tblk, 0, stream>>>(W, Wt);

    if (f16path) {
        // Xb (67 MB bf16) lives in the out buffer as scratch; dead before scan writes out.
        unsigned short* Xb = (unsigned short*)out;
        xb_kernel<<<2048, 256, 0, stream>>>(x, Xb);
        gemm_xb_kernel<<<2048, 256, 0, stream>>>(Xb, Wt, b, xp16);
        scan_t_kernel<<<512, 64, 0, stream>>>(xp16, out, u);
    } else {
        gemm_f32_kernel<<<2048, 256, 0, stream>>>(x, Wt, b, out);
        scan_f32_kernel<<<512, 64, 0, stream>>>(out, u);
    }
}